// Round 7
// baseline (1111.557 us; speedup 1.0000x reference)
//
#include <hip/hip_runtime.h>
#include <hip/hip_fp16.h>

// LSTM: B=512, T=1024, I=64, H=128, C=10
// Persistent kernel: 32 WGs x 256 threads (4 waves, 1/SIMD); each WG owns 16
// batch rows for the whole sequence. Weights resident in VGPRs as fp16 MFMA
// B-fragments, PRE-SCALED by log2(e) (2*log2(e) for the g-gate) so the gate
// nonlinearities use raw v_exp_f32 (exp2) + v_rcp_f32 -- no IEEE divides, no
// per-element log2e multiplies. Each wave owns a 32-wide jh slice x 4 gates
// (48 fragments); A-fragments are shared across jt so each wave issues only
// 6 ds_read_b128 per step -> 24/CU (halved LDS port traffic vs 8-wave).
// h written back to LDS fp16 (double-buffered, XOR-swizzled -> conflict-free);
// ONE barrier per step; LDS addresses hoisted; 2-step unroll for compile-time
// buffer parity; x(t) via depth-2 float4 register FIFO.

typedef _Float16 f16x8 __attribute__((ext_vector_type(8)));
typedef _Float16 f16x4 __attribute__((ext_vector_type(4)));
typedef __fp16   hf2   __attribute__((ext_vector_type(2)));   // cvt_pkrtz native type
typedef float    f32x4 __attribute__((ext_vector_type(4)));

constexpr int Bc   = 16;    // batch rows per workgroup (MFMA M)
constexpr int Tn   = 1024;
constexpr int In   = 64;
constexpr int Hn   = 128;
constexpr int Cn   = 10;
constexpr int Kn   = 192;   // I + H
constexpr int ROWB = Kn * 2;      // 384 bytes per row
constexpr int BUFB = Bc * ROWB;   // 6144 bytes per buffer

// XOR swizzle: spreads the 8-row bank alias (384 % 128 == 0) of the
// transpose-pattern ds_read_b128. Bijective per row; flips byte bits 4..6.
__device__ __forceinline__ int swz(int row, int byteInRow) {
    return row * ROWB + (byteInRow ^ ((row & 7) << 4));
}

__global__ __launch_bounds__(256, 1)
void lstm_persist(const float* __restrict__ x,
                  const float* __restrict__ Wf, const float* __restrict__ bf,
                  const float* __restrict__ Wo, const float* __restrict__ bo,
                  const float* __restrict__ Wi, const float* __restrict__ bi,
                  const float* __restrict__ Wg, const float* __restrict__ bg,
                  const float* __restrict__ Wfc, const float* __restrict__ bfc,
                  float* __restrict__ out)
{
    __shared__ __align__(16) char comb[2 * BUFB];   // fp16 [row][x(64)|h(128)], swizzled
    __shared__ float h32[Bc][Hn];                   // final-step h, fp32

    const int tid  = threadIdx.x;
    const int lane = tid & 63;
    const int wv   = tid >> 6;        // wave 0..3 -> owns jh in [32*wv, 32*wv+32)
    const int l15  = lane & 15;
    const int lg   = lane >> 4;       // k-group 0..3
    const int b0   = blockIdx.x * Bc;
    const int jh0  = wv * 32;

    // ---- weight fragments (fp16, log2e-scaled) into registers, once ----
    // wfrag[gt][kt][jt]: lane l holds s_gt * W[jh0 + jt*16 + l15][kt*32 + lg*8 + e]
    const float* Wptr[4] = {Wf, Wo, Wi, Wg};
    const float* bptr[4] = {bf, bo, bi, bg};
    f16x8 wfrag[4][6][2];
    float bias[4][2];
#pragma unroll
    for (int gt = 0; gt < 4; ++gt) {
        const float* W = Wptr[gt];
        const float s = (gt == 3) ? 2.8853900817779268f : 1.4426950408889634f;
#pragma unroll
        for (int jt = 0; jt < 2; ++jt) {
            const int jrow = jh0 + jt * 16 + l15;
#pragma unroll
            for (int kt = 0; kt < 6; ++kt) {
                const int base = jrow * Kn + kt * 32 + lg * 8;
                const float4 w0 = *reinterpret_cast<const float4*>(&W[base]);
                const float4 w1 = *reinterpret_cast<const float4*>(&W[base + 4]);
                f16x8 h;
                h[0] = (_Float16)(w0.x * s); h[1] = (_Float16)(w0.y * s);
                h[2] = (_Float16)(w0.z * s); h[3] = (_Float16)(w0.w * s);
                h[4] = (_Float16)(w1.x * s); h[5] = (_Float16)(w1.y * s);
                h[6] = (_Float16)(w1.z * s); h[7] = (_Float16)(w1.w * s);
                wfrag[gt][kt][jt] = h;
            }
            bias[gt][jt] = bptr[gt][jrow] * s;
        }
    }

    // ---- hoisted LDS byte offsets (compile-time indexed only) ----
    const int xrow = tid >> 4;          // 0..15
    const int xi0  = (tid & 15) * 4;    // x col base (float4 granularity)
    int addrA[2][6], addrH[2][8], addrX[2];
#pragma unroll
    for (int kt = 0; kt < 6; ++kt) {
        const int o = swz(l15, (kt * 32 + lg * 8) * 2);
        addrA[0][kt] = o; addrA[1][kt] = BUFB + o;
    }
#pragma unroll
    for (int jt = 0; jt < 2; ++jt)
#pragma unroll
        for (int r = 0; r < 4; ++r) {
            const int o = swz(lg * 4 + r, (In + jh0 + jt * 16 + l15) * 2);
            addrH[0][jt * 4 + r] = o; addrH[1][jt * 4 + r] = BUFB + o;
        }
    {
        const int o = swz(xrow, xi0 * 2);
        addrX[0] = o; addrX[1] = BUFB + o;
    }

    // ---- init: zero buffer 0, stage x(0), c = 0 ----
    float c[2][4], hreg[2][4];
#pragma unroll
    for (int jt = 0; jt < 2; ++jt)
#pragma unroll
        for (int r = 0; r < 4; ++r) { c[jt][r] = 0.f; hreg[jt][r] = 0.f; }
    {
        for (int o = tid * 8; o < BUFB; o += 256 * 8)
            *reinterpret_cast<unsigned long long*>(comb + o) = 0ull;
    }
    __syncthreads();
    {
        const float4 xv = *reinterpret_cast<const float4*>(
            &x[((size_t)(b0 + xrow) * Tn + 0) * In + xi0]);
        const hf2 p0 = __builtin_amdgcn_cvt_pkrtz(xv.x, xv.y);
        const hf2 p1 = __builtin_amdgcn_cvt_pkrtz(xv.z, xv.w);
        f16x4 pk;
        pk[0] = (_Float16)p0[0]; pk[1] = (_Float16)p0[1];
        pk[2] = (_Float16)p1[0]; pk[3] = (_Float16)p1[1];
        *reinterpret_cast<f16x4*>(comb + addrX[0]) = pk;
    }

    // x register FIFO: xv0 = x(t+1), xv1 = x(t+2)
    const float* xbase = &x[(size_t)(b0 + xrow) * Tn * In + xi0];
    float4 xv0 = *reinterpret_cast<const float4*>(&xbase[(size_t)1 * In]);
    float4 xv1 = *reinterpret_cast<const float4*>(&xbase[(size_t)2 * In]);

    __syncthreads();

    // ---- time loop: explicit 2-step unroll, P = buffer parity (literal) ----
#define LSTM_STEP(P, T)                                                        \
    {                                                                          \
        /* stage x(T+1) into buffer P^1; refill FIFO with x(T+3) */            \
        {                                                                      \
            const hf2 p0 = __builtin_amdgcn_cvt_pkrtz(xv0.x, xv0.y);           \
            const hf2 p1 = __builtin_amdgcn_cvt_pkrtz(xv0.z, xv0.w);           \
            f16x4 pk;                                                          \
            pk[0] = (_Float16)p0[0]; pk[1] = (_Float16)p0[1];                  \
            pk[2] = (_Float16)p1[0]; pk[3] = (_Float16)p1[1];                  \
            *reinterpret_cast<f16x4*>(comb + addrX[(P) ^ 1]) = pk;             \
        }                                                                      \
        xv0 = xv1;                                                             \
        {                                                                      \
            const int tf = ((T) + 3 < Tn) ? (T) + 3 : (Tn - 1);                \
            xv1 = *reinterpret_cast<const float4*>(&xbase[(size_t)tf * In]);   \
        }                                                                      \
        f16x8 a[6];                                                            \
        _Pragma("unroll")                                                      \
        for (int kt = 0; kt < 6; ++kt)                                         \
            a[kt] = *reinterpret_cast<const f16x8*>(comb + addrA[P][kt]);      \
        f32x4 acc[4][2];                                                       \
        _Pragma("unroll")                                                      \
        for (int gt = 0; gt < 4; ++gt)                                         \
            _Pragma("unroll")                                                  \
            for (int jt = 0; jt < 2; ++jt) {                                   \
                const float bb = bias[gt][jt];                                 \
                acc[gt][jt] = (f32x4){bb, bb, bb, bb};                         \
            }                                                                  \
        _Pragma("unroll")                                                      \
        for (int kt = 0; kt < 6; ++kt)                                         \
            _Pragma("unroll")                                                  \
            for (int gt = 0; gt < 4; ++gt)                                     \
                _Pragma("unroll")                                              \
                for (int jt = 0; jt < 2; ++jt)                                 \
                    acc[gt][jt] = __builtin_amdgcn_mfma_f32_16x16x32_f16(      \
                        a[kt], wfrag[gt][kt][jt], acc[gt][jt], 0, 0, 0);       \
        /* gates (log2e pre-folded): sig = rcp(1+2^-y'), tanh = 1-2*rcp(1+2^y')\
           D layout: reg r, lane l -> batch row = lg*4+r, jh = jh0+jt*16+l15 */\
        _Pragma("unroll")                                                      \
        for (int jt = 0; jt < 2; ++jt)                                         \
            _Pragma("unroll")                                                  \
            for (int r = 0; r < 4; ++r) {                                      \
                const float fg = __builtin_amdgcn_rcpf(                        \
                    1.f + __builtin_amdgcn_exp2f(-acc[0][jt][r]));             \
                const float og = __builtin_amdgcn_rcpf(                        \
                    1.f + __builtin_amdgcn_exp2f(-acc[1][jt][r]));             \
                const float ig = __builtin_amdgcn_rcpf(                        \
                    1.f + __builtin_amdgcn_exp2f(-acc[2][jt][r]));             \
                const float gg = fmaf(                                         \
                    -2.f, __builtin_amdgcn_rcpf(                               \
                              1.f + __builtin_amdgcn_exp2f(acc[3][jt][r])),    \
                    1.f);                                                      \
                c[jt][r]    = fmaf(c[jt][r], fg, ig * gg);                     \
                hreg[jt][r] = c[jt][r] * og;                                   \
                *reinterpret_cast<_Float16*>(                                  \
                    comb + addrH[(P) ^ 1][jt * 4 + r]) = (_Float16)hreg[jt][r];\
            }                                                                  \
        __syncthreads();                                                       \
    }

    for (int t = 0; t < Tn; t += 2) {
        LSTM_STEP(0, t)
        LSTM_STEP(1, t + 1)
    }
#undef LSTM_STEP

    // ---- final FC: out = h @ Wfc^T + bfc, using fp32 h ----
#pragma unroll
    for (int jt = 0; jt < 2; ++jt)
#pragma unroll
        for (int r = 0; r < 4; ++r)
            h32[lg * 4 + r][jh0 + jt * 16 + l15] = hreg[jt][r];
    __syncthreads();

    if (tid < Bc * Cn) {
        const int row = tid / Cn;
        const int cc  = tid % Cn;
        float a2 = bfc[cc];
#pragma unroll 4
        for (int jh = 0; jh < Hn; ++jh)
            a2 += h32[row][jh] * Wfc[cc * Hn + jh];
        out[(size_t)(b0 + row) * Cn + cc] = a2;
    }
}

extern "C" void kernel_launch(void* const* d_in, const int* in_sizes, int n_in,
                              void* d_out, int out_size, void* d_ws, size_t ws_size,
                              hipStream_t stream) {
    const float* xp  = (const float*)d_in[0];
    const float* Wfp = (const float*)d_in[1];
    const float* bfp = (const float*)d_in[2];
    const float* Wop = (const float*)d_in[3];
    const float* bop = (const float*)d_in[4];
    const float* Wip = (const float*)d_in[5];
    const float* bip = (const float*)d_in[6];
    const float* Wgp = (const float*)d_in[7];
    const float* bgp = (const float*)d_in[8];
    const float* Wfc = (const float*)d_in[9];
    const float* bfc = (const float*)d_in[10];
    float* outp = (float*)d_out;

    lstm_persist<<<512 / Bc, 256, 0, stream>>>(xp, Wfp, bfp, Wop, bop, Wip, bip,
                                               Wgp, bgp, Wfc, bfc, outp);
}